// Round 16
// baseline (237.044 us; speedup 1.0000x reference)
//
#include <hip/hip_runtime.h>
#include <hip/hip_bf16.h>
#include <stdint.h>

#define NPTS 131072
#define DIM  512
#define KC   512
#define BM   32
#define NQ   32          // DIM / 16 : number of BK=16 phases

typedef float f32x16 __attribute__((ext_vector_type(16)));
typedef float f32x4  __attribute__((ext_vector_type(4)));
typedef short bf16x8 __attribute__((ext_vector_type(8)));

__device__ __forceinline__ float sq4(f32x4 a) {
  return a.x*a.x + a.y*a.y + a.z*a.z + a.w*a.w;
}

// packed RNE fp32->bf16 (v_cvt_pk_bf16_f32)
__device__ __forceinline__ bf16x8 pack8c(f32x4 a, f32x4 b) {
  union { __hip_bfloat162 h; short s[2]; } u0, u1, u2, u3;
  u0.h = __float22bfloat162_rn(make_float2(a.x, a.y));
  u1.h = __float22bfloat162_rn(make_float2(a.z, a.w));
  u2.h = __float22bfloat162_rn(make_float2(b.x, b.y));
  u3.h = __float22bfloat162_rn(make_float2(b.z, b.w));
  bf16x8 r;
  r[0] = u0.s[0]; r[1] = u0.s[1]; r[2] = u1.s[0]; r[3] = u1.s[1];
  r[4] = u2.s[0]; r[5] = u2.s[1]; r[6] = u3.s[0]; r[7] = u3.s[1];
  return r;
}

// scalar RNE (cluster pre-kernel only)
__device__ __forceinline__ short f2bf(float f) {
  union { float f; unsigned u; } v; v.f = f;
  unsigned r = v.u + 0x7FFFu + ((v.u >> 16) & 1u);
  return (short)(r >> 16);
}
__device__ __forceinline__ bf16x8 pack8(f32x4 a, f32x4 b) {
  bf16x8 p;
  p[0] = f2bf(a.x); p[1] = f2bf(a.y); p[2] = f2bf(a.z); p[3] = f2bf(a.w);
  p[4] = f2bf(b.x); p[5] = f2bf(b.y); p[6] = f2bf(b.z); p[7] = f2bf(b.w);
  return p;
}

__device__ __forceinline__ void gload_lds16(const void* g, void* l) {
  __builtin_amdgcn_global_load_lds(
      (const __attribute__((address_space(1))) unsigned int*)g,
      (__attribute__((address_space(3))) unsigned int*)l, 16, 0, 0);
}

// ---------------------------------------------------------------------------
// Cluster pre-kernel (layout verified R5-R15, unchanged): fp32 [512][512] ->
// bf16 in MFMA-B-fragment order. Short offset = q*8192 + wn*2048 + nt*512 +
// (h*32+r)*8 where q = k/16. For a fixed wn, the quarter within each q-tile
// is a CONTIGUOUS 4 KB run — exactly what one wave stages privately.
// c2[n] = ||c_n||^2 fp32.
// ---------------------------------------------------------------------------
__global__ void dec_pack(const float* __restrict__ C, short* __restrict__ Bp,
                         float* __restrict__ c2) {
  const int n    = blockIdx.x;
  const int lane = threadIdx.x;
  const float* src = C + (size_t)n * DIM + lane * 8;
  f32x4 v0 = *(const f32x4*)src;
  f32x4 v1 = *(const f32x4*)(src + 4);
  float s = sq4(v0) + sq4(v1);
  #pragma unroll
  for (int m = 1; m < 64; m <<= 1) s += __shfl_xor(s, m, 64);
  if (lane == 0) c2[n] = s;
  const int kt = lane >> 2;
  const int st = (lane >> 1) & 1;
  const int hh = lane & 1;
  const int wn = n >> 7, nt = (n >> 5) & 3, r = n & 31;
  const size_t slot =
      (((size_t)(kt * 2 + st) * 4 + wn) * 4 + nt) * 64 + hh * 32 + r;
  *(bf16x8*)(Bp + slot * 8) = pack8(v0, v1);
}

// ---------------------------------------------------------------------------
// Main fused kernel (R16): ZERO barriers in the K loop — every staging
// buffer is WAVE-PRIVATE; waves run fully decoupled pipelines.
// 256 threads = 4 waves (wn = wave); block tile 32 x 512 (full cluster
// width -> block-local normalization). Wave tile 32 x 128:
// 4 x mfma_f32_32x32x16_bf16 per phase (BK=16), acc = 4 x f32x16 (64 AGPR).
//
// Per wave per phase q: 6 global_load_lds ops stage phase q+2 —
//   B-quarter: 4 x 1 KB from the contiguous pre-packed run (ring-3 x 4 KB);
//   A-slice:   2 x 1 KB fp32 (rows 0-15 / 16-31, chunk XOR ^(row&3),
//              ring-3 x 2 KB) — 16 fully-used 64B sectors per op.
// All dests obey the lane*16 contract (linear, wave-uniform base).
// Wait: per-wave asm vmcnt(6) (keeps last phase's 6 in flight; slot q
// staged 2 phases ago guaranteed landed). Same-wave ring reuse is safe
// WITHOUT barriers: lgkmcnt before phase p's MFMAs retires its ds_reads
// before phase p+1's gloads (program order) can overwrite the slot.
// Compute: 2 x f32x4 A-frag reads (XOR ^(l31&3), 8-sweep minimal) ->
// cvt_pk; 4 x b128 B-frag reads (linear); 4 MFMA; x2 fused (fp32 exact).
// LDS: 4 waves x (12 KB B-ring + 6 KB A-ring) + 0.6 KB epi = 72.6 KB
// -> 2 blocks/CU, 8 decoupled wave-pipelines per CU. ~110 regs.
// One __syncthreads total (epilogue row-sum combine).
// ---------------------------------------------------------------------------
__global__ __launch_bounds__(256)
void dec_main(const float* __restrict__ X, const short* __restrict__ Bp,
              const float* __restrict__ c2g, float* __restrict__ out) {
  __shared__ short Bpriv[4][3][2048];   // [wave][slot][4 KB]
  __shared__ float Apriv[4][3][512];    // [wave][slot][2 KB]
  __shared__ float part[4][BM];
  __shared__ float rowinv[BM];

  const int tid  = threadIdx.x;
  const int lane = tid & 63;
  const int wn   = tid >> 6;    // 0..3 : column quarter (one wave each)
  const int l31  = lane & 31;
  const int h    = lane >> 5;
  const int row0 = blockIdx.x * BM;

  // B staging source: wave's contiguous 4 KB quarter of each q-tile
  const short* bsrc = Bp + wn * 2048 + lane * 8;   // + q*8192 + s*512
  // A staging: op o covers row o*16 + (lane>>2), 16B chunk (lane&3),
  // source chunk pre-swizzled ^(row&3); 64B/row = one full sector.
  const int ar4  = lane >> 2;                       // 0..15
  const int acsw = (lane & 3) ^ (ar4 & 3);
  const float* asrc0 = X + (size_t)(row0 + ar4) * DIM + acsw * 4;
  const float* asrc1 = X + (size_t)(row0 + 16 + ar4) * DIM + acsw * 4;
  const int rdsw = l31 & 3;     // read-side chunk XOR

  f32x16 acc[4];
  #pragma unroll
  for (int nt = 0; nt < 4; ++nt) acc[nt] = (f32x16)0.f;
  float x2 = 0.f;

  // stage phase qq (clamped) into ring slot `slot` — 6 wave-private ops
#define STAGE(qq, slot)                                                   \
  {                                                                       \
    const int q_ = ((qq) < NQ) ? (qq) : NQ - 1;                           \
    _Pragma("unroll")                                                     \
    for (int s = 0; s < 4; ++s)                                           \
      gload_lds16(bsrc + (size_t)q_ * 8192 + s * 512,                     \
                  &Bpriv[wn][slot][s * 512 + lane * 8]);                  \
    gload_lds16(asrc0 + q_ * 16, &Apriv[wn][slot][lane * 4]);             \
    gload_lds16(asrc1 + q_ * 16, &Apriv[wn][slot][256 + lane * 4]);       \
  }

  // ---- prologue: stage q=0 and q=1 (12 ops outstanding) ----
  STAGE(0, 0);
  __builtin_amdgcn_sched_barrier(0);
  STAGE(1, 1);
  __builtin_amdgcn_sched_barrier(0);

  // ---- K loop: 32 phases, fully unrolled, NO barriers ----
  #pragma unroll
  for (int q = 0; q < NQ; ++q) {
    const int sl = q % 3;
    const int st = (q + 2) % 3;

    // slot sl (staged 2 phases ago) landed; last phase's 6 stay in flight
    asm volatile("s_waitcnt vmcnt(6)" ::: "memory");
    __builtin_amdgcn_sched_barrier(0);
    STAGE(q + 2, st);
    __builtin_amdgcn_sched_barrier(0);
    {
      const float* A = &Apriv[wn][sl][0];
      f32x4 lo = *(const f32x4*)&A[l31 * 16 + (((h * 2 + 0) ^ rdsw) << 2)];
      f32x4 hi = *(const f32x4*)&A[l31 * 16 + (((h * 2 + 1) ^ rdsw) << 2)];
      x2 += sq4(lo) + sq4(hi);
      bf16x8 af = pack8c(lo, hi);
      bf16x8 bfr[4];
      #pragma unroll
      for (int nt = 0; nt < 4; ++nt)
        bfr[nt] = *(const bf16x8*)&Bpriv[wn][sl][nt * 512 + lane * 8];
      #pragma unroll
      for (int nt = 0; nt < 4; ++nt)
        acc[nt] = __builtin_amdgcn_mfma_f32_32x32x16_bf16(
            af, bfr[nt], acc[nt], 0, 0, 0);
    }
  }
#undef STAGE

  // ---- x2: combine the two k-halves; lane l31 holds x2(row l31) ----
  x2 += __shfl_xor(x2, 32, 64);

  float c2v[4];
  #pragma unroll
  for (int nt = 0; nt < 4; ++nt) c2v[nt] = c2g[wn * 128 + nt * 32 + l31];

  // ---- q = rcp(1+d2), per-row partial sums over this wave's 128 cols ----
  float srow[16];
  #pragma unroll
  for (int r = 0; r < 16; ++r) {
    const int mloc = (r & 3) + 8 * (r >> 2) + 4 * h;   // 0..31
    const float x2m = __shfl(x2, mloc, 64);
    float s = 0.f;
    #pragma unroll
    for (int nt = 0; nt < 4; ++nt) {
      float d2 = fmaxf(x2m + c2v[nt] - 2.f * acc[nt][r], 0.f);
      float qv = __builtin_amdgcn_rcpf(1.f + d2);
      acc[nt][r] = qv;
      s += qv;
    }
    #pragma unroll
    for (int msk = 1; msk < 32; msk <<= 1) s += __shfl_xor(s, msk, 64);
    srow[r] = s;
  }

  if (l31 == 0) {
    #pragma unroll
    for (int r = 0; r < 16; ++r)
      part[wn][(r & 3) + 8 * (r >> 2) + 4 * h] = srow[r];
  }
  __syncthreads();    // drains dead tail stages + publishes partials
  if (tid < BM)
    rowinv[tid] = __builtin_amdgcn_rcpf(part[0][tid] + part[1][tid] +
                                        part[2][tid] + part[3][tid]);
  __syncthreads();

  // ---- normalize + coalesced stores ----
  #pragma unroll
  for (int r = 0; r < 16; ++r) {
    const int row = (r & 3) + 8 * (r >> 2) + 4 * h;
    const float iv = rowinv[row];
    float* o = out + (size_t)(row0 + row) * KC + wn * 128 + l31;
    #pragma unroll
    for (int nt = 0; nt < 4; ++nt)
      o[nt * 32] = acc[nt][r] * iv;
  }
}

extern "C" void kernel_launch(void* const* d_in, const int* in_sizes, int n_in,
                              void* d_out, int out_size, void* d_ws, size_t ws_size,
                              hipStream_t stream) {
  const float* X = (const float*)d_in[0];   // inputs  [131072, 512] fp32
  const float* C = (const float*)d_in[1];   // clusters [512, 512] fp32
  float* out = (float*)d_out;               // [131072, 512] fp32

  short* Bp = (short*)d_ws;                                   // 512 KB packed bf16 clusters
  float* c2 = (float*)((char*)d_ws + (size_t)KC * DIM * 2);   // 2 KB cluster norms

  dec_pack<<<KC, 64, 0, stream>>>(C, Bp, c2);
  dec_main<<<NPTS / BM, 256, 0, stream>>>(X, Bp, c2, out);
}

// Round 17
// 174.210 us; speedup vs baseline: 1.3607x; 1.3607x over previous
//
#include <hip/hip_runtime.h>
#include <hip/hip_bf16.h>
#include <stdint.h>

#define NPTS 131072
#define DIM  512
#define KC   512
#define BM   64
#define BK   32
#define NKT  16          // DIM / BK

typedef float f32x16 __attribute__((ext_vector_type(16)));
typedef float f32x4  __attribute__((ext_vector_type(4)));
typedef short bf16x8 __attribute__((ext_vector_type(8)));

__device__ __forceinline__ float sq4(f32x4 a) {
  return a.x*a.x + a.y*a.y + a.z*a.z + a.w*a.w;
}

// packed RNE fp32->bf16 (v_cvt_pk_bf16_f32)
__device__ __forceinline__ bf16x8 pack8c(f32x4 a, f32x4 b) {
  union { __hip_bfloat162 h; short s[2]; } u0, u1, u2, u3;
  u0.h = __float22bfloat162_rn(make_float2(a.x, a.y));
  u1.h = __float22bfloat162_rn(make_float2(a.z, a.w));
  u2.h = __float22bfloat162_rn(make_float2(b.x, b.y));
  u3.h = __float22bfloat162_rn(make_float2(b.z, b.w));
  bf16x8 r;
  r[0] = u0.s[0]; r[1] = u0.s[1]; r[2] = u1.s[0]; r[3] = u1.s[1];
  r[4] = u2.s[0]; r[5] = u2.s[1]; r[6] = u3.s[0]; r[7] = u3.s[1];
  return r;
}

// scalar RNE (cluster pre-kernel only)
__device__ __forceinline__ short f2bf(float f) {
  union { float f; unsigned u; } v; v.f = f;
  unsigned r = v.u + 0x7FFFu + ((v.u >> 16) & 1u);
  return (short)(r >> 16);
}
__device__ __forceinline__ bf16x8 pack8(f32x4 a, f32x4 b) {
  bf16x8 p;
  p[0] = f2bf(a.x); p[1] = f2bf(a.y); p[2] = f2bf(a.z); p[3] = f2bf(a.w);
  p[4] = f2bf(b.x); p[5] = f2bf(b.y); p[6] = f2bf(b.z); p[7] = f2bf(b.w);
  return p;
}

__device__ __forceinline__ void gload_lds16(const void* g, void* l) {
  __builtin_amdgcn_global_load_lds(
      (const __attribute__((address_space(1))) unsigned int*)g,
      (__attribute__((address_space(3))) unsigned int*)l, 16, 0, 0);
}

// ---------------------------------------------------------------------------
// Cluster pre-kernel (layout verified R5-R16): fp32 [512][512] -> bf16 in
// MFMA-B-fragment order. Short offset = q*8192 + wn*2048 + nt*512 +
// (h*32+r)*8 where q = kt*2+st is the HALF-KT index — each 16 KB half-tile
// is contiguous, staged linearly, fragments read at base + lane*16.
// c2[n] = ||c_n||^2 fp32.
// ---------------------------------------------------------------------------
__global__ void dec_pack(const float* __restrict__ C, short* __restrict__ Bp,
                         float* __restrict__ c2) {
  const int n    = blockIdx.x;
  const int lane = threadIdx.x;
  const float* src = C + (size_t)n * DIM + lane * 8;
  f32x4 v0 = *(const f32x4*)src;
  f32x4 v1 = *(const f32x4*)(src + 4);
  float s = sq4(v0) + sq4(v1);
  #pragma unroll
  for (int m = 1; m < 64; m <<= 1) s += __shfl_xor(s, m, 64);
  if (lane == 0) c2[n] = s;
  const int kt = lane >> 2;
  const int st = (lane >> 1) & 1;
  const int hh = lane & 1;
  const int wn = n >> 7, nt = (n >> 5) & 3, r = n & 31;
  const size_t slot =
      (((size_t)(kt * 2 + st) * 4 + wn) * 4 + nt) * 64 + hh * 32 + r;
  *(bf16x8*)(Bp + slot * 8) = pack8(v0, v1);
}

// ---------------------------------------------------------------------------
// Main fused kernel (R18 = R11 [172 us champion] + T5 s_setprio around the
// MFMA clusters — single-variable A/B change).
// 512 threads = 8 waves (wm = wave>>2, wn = wave&3); block tile 64 x 512.
// Wave tile 32x128; 4 MFMA per phase, 2 phases (s = 0,1) per kt.
//
// 32 phases. Phase p body:  [s_waitcnt vmcnt(N); s_barrier]  ->
//   [stage: even p: B-half(p+2) 2x gload_lds + A(kt+1) 1x gload_lds;
//           odd  p: B-half(p+2) 2x gload_lds]                ->
//   [compute(kt, s=p&1): 2x ds_read_b128 fp32 A-frag (XOR-swizzled) ->
//    cvt_pk -> 4x ds_read_b128 B-frag (linear) -> setprio(1) 4 MFMA
//    setprio(0); x2 fused].
// N = ops staged in phase p-1 (even->2 entering odd, odd->3 entering even):
// every buffer waited on is one full phase old; no vmcnt(0) drain in loop.
// Rings: B 3 x 16 KB (stage->use distance 2 phases), A fp32 2 x 8 KB.
// LDS 64 KB -> 2 blocks/CU; VGPR 64 + 64 AGPR -> 16 waves/CU.
// Dead-tail stages keep counts uniform; final __syncthreads drains them.
// ---------------------------------------------------------------------------
__global__ __launch_bounds__(512, 4)
void dec_main(const float* __restrict__ X, const short* __restrict__ Bp,
              const float* __restrict__ c2g, float* __restrict__ out) {
  __shared__ short Bh[3][8192];     // 3 x 16 KB half-kt B tiles
  __shared__ float Ab[2][2048];     // 2 x 8 KB fp32 A tiles (swizzled chunks)

  const int tid  = threadIdx.x;
  const int lane = tid & 63;
  const int wave = tid >> 6;
  const int wm   = wave >> 2;   // 0..1 : row half
  const int wn   = wave & 3;    // 0..3 : column quarter
  const int l31  = lane & 31;
  const int h    = lane >> 5;
  const int row0 = blockIdx.x * BM;

  // A staging: thread t -> row (t>>3), source chunk ((t&7)^((t>>3)&7)),
  // dest linear t*16B (lane*16 contract; source-side XOR swizzle).
  const float* asrc = X + (size_t)(row0 + (tid >> 3)) * DIM +
                      (((tid & 7) ^ ((tid >> 3) & 7)) << 2);
  // B staging: half-tile q -> 2 x 16B/thread, linear
  const short* bsrc = Bp + tid * 8;

  // A fragment read base (floats): row (wm*32+l31)
  const int abase = (wm * 32 + l31) * BK;
  const int asw   = l31 & 7;    // read-side XOR

  f32x16 acc[4];
  #pragma unroll
  for (int nt = 0; nt < 4; ++nt) acc[nt] = (f32x16)0.f;
  float x2 = 0.f;

  // ---- prologue: stage q=0 (+A(0)), then q=1; matches steady-state counts
  gload_lds16(bsrc, &Bh[0][tid * 8]);
  gload_lds16(bsrc + 4096, &Bh[0][4096 + tid * 8]);
  gload_lds16(asrc, &Ab[0][tid * 4]);
  __builtin_amdgcn_sched_barrier(0);
  gload_lds16(bsrc + 8192, &Bh[1][tid * 8]);
  gload_lds16(bsrc + 8192 + 4096, &Bh[1][4096 + tid * 8]);
  __builtin_amdgcn_sched_barrier(0);

  int rb = 0;   // Bh ring position of (kt, s=0)
  for (int kt = 0; kt < NKT; ++kt) {
    const int rb1 = (rb == 2) ? 0 : rb + 1;   // (kt,s=1) buffer
    const int rb2 = (rb == 0) ? 2 : rb - 1;   // stage target for even phase

    // ================= even phase p = 2kt =================
    asm volatile("s_waitcnt vmcnt(2)" ::: "memory");
    __builtin_amdgcn_sched_barrier(0);
    __builtin_amdgcn_s_barrier();
    __builtin_amdgcn_sched_barrier(0);
    {
      const int q  = (2 * kt + 2 < 32) ? 2 * kt + 2 : 31;   // B half index
      const int ka = (kt + 1 < NKT) ? kt + 1 : NKT - 1;     // A tile index
      gload_lds16(bsrc + (size_t)q * 8192, &Bh[rb2][tid * 8]);
      gload_lds16(bsrc + (size_t)q * 8192 + 4096, &Bh[rb2][4096 + tid * 8]);
      gload_lds16(asrc + ka * BK, &Ab[(kt + 1) & 1][tid * 4]);
    }
    __builtin_amdgcn_sched_barrier(0);
    {
      const float* A = &Ab[kt & 1][0];
      f32x4 lo = *(const f32x4*)&A[abase + (((h * 2 + 0) ^ asw) << 2)];
      f32x4 hi = *(const f32x4*)&A[abase + (((h * 2 + 1) ^ asw) << 2)];
      x2 += sq4(lo) + sq4(hi);
      bf16x8 af = pack8c(lo, hi);
      bf16x8 bfr[4];
      #pragma unroll
      for (int nt = 0; nt < 4; ++nt)
        bfr[nt] = *(const bf16x8*)&Bh[rb][(wn * 4 + nt) * 512 + lane * 8];
      __builtin_amdgcn_s_setprio(1);
      #pragma unroll
      for (int nt = 0; nt < 4; ++nt)
        acc[nt] = __builtin_amdgcn_mfma_f32_32x32x16_bf16(
            af, bfr[nt], acc[nt], 0, 0, 0);
      __builtin_amdgcn_s_setprio(0);
    }

    // ================= odd phase p = 2kt+1 =================
    asm volatile("s_waitcnt vmcnt(3)" ::: "memory");
    __builtin_amdgcn_sched_barrier(0);
    __builtin_amdgcn_s_barrier();
    __builtin_amdgcn_sched_barrier(0);
    {
      const int q = (2 * kt + 3 < 32) ? 2 * kt + 3 : 31;
      gload_lds16(bsrc + (size_t)q * 8192, &Bh[rb][tid * 8]);
      gload_lds16(bsrc + (size_t)q * 8192 + 4096, &Bh[rb][4096 + tid * 8]);
    }
    __builtin_amdgcn_sched_barrier(0);
    {
      const float* A = &Ab[kt & 1][0];
      f32x4 lo = *(const f32x4*)&A[abase + (((4 + h * 2 + 0) ^ asw) << 2)];
      f32x4 hi = *(const f32x4*)&A[abase + (((4 + h * 2 + 1) ^ asw) << 2)];
      x2 += sq4(lo) + sq4(hi);
      bf16x8 af = pack8c(lo, hi);
      bf16x8 bfr[4];
      #pragma unroll
      for (int nt = 0; nt < 4; ++nt)
        bfr[nt] = *(const bf16x8*)&Bh[rb1][(wn * 4 + nt) * 512 + lane * 8];
      __builtin_amdgcn_s_setprio(1);
      #pragma unroll
      for (int nt = 0; nt < 4; ++nt)
        acc[nt] = __builtin_amdgcn_mfma_f32_32x32x16_bf16(
            af, bfr[nt], acc[nt], 0, 0, 0);
      __builtin_amdgcn_s_setprio(0);
    }

    rb = (rb + 2 >= 3) ? rb - 1 : rb + 2;   // (rb + 2) % 3
  }

  // drain dead tail stages before overlaying epilogue scratch on Ab
  __syncthreads();

  // ---- x2: combine the two k-halves; lane l31 holds x2(row wm*32+l31) ----
  x2 += __shfl_xor(x2, 32, 64);

  float c2v[4];
  #pragma unroll
  for (int nt = 0; nt < 4; ++nt) c2v[nt] = c2g[wn * 128 + nt * 32 + l31];

  // ---- q = rcp(1+d2), per-row partial sums over this wave's 128 cols ----
  float srow[16];
  #pragma unroll
  for (int r = 0; r < 16; ++r) {
    const int mloc = (r & 3) + 8 * (r >> 2) + 4 * h;   // 0..31
    const float x2m = __shfl(x2, mloc, 64);
    float s = 0.f;
    #pragma unroll
    for (int nt = 0; nt < 4; ++nt) {
      float d2 = fmaxf(x2m + c2v[nt] - 2.f * acc[nt][r], 0.f);
      float q = __builtin_amdgcn_rcpf(1.f + d2);
      acc[nt][r] = q;
      s += q;
    }
    #pragma unroll
    for (int msk = 1; msk < 32; msk <<= 1) s += __shfl_xor(s, msk, 64);
    srow[r] = s;
  }

  // epilogue scratch overlaid on Ab (dead after the drain barrier)
  float* part   = &Ab[0][0];        // [4][BM]
  float* rowinv = &Ab[0][4 * BM];

  if (l31 == 0) {
    #pragma unroll
    for (int r = 0; r < 16; ++r)
      part[wn * BM + wm * 32 + (r & 3) + 8 * (r >> 2) + 4 * h] = srow[r];
  }
  __syncthreads();
  if (tid < BM)
    rowinv[tid] = __builtin_amdgcn_rcpf(part[tid] + part[BM + tid] +
                                        part[2 * BM + tid] + part[3 * BM + tid]);
  __syncthreads();

  // ---- normalize + coalesced stores ----
  #pragma unroll
  for (int r = 0; r < 16; ++r) {
    const int row = wm * 32 + (r & 3) + 8 * (r >> 2) + 4 * h;
    const float iv = rowinv[row];
    float* o = out + (size_t)(row0 + row) * KC + wn * 128 + l31;
    #pragma unroll
    for (int nt = 0; nt < 4; ++nt)
      o[nt * 32] = acc[nt][r] * iv;
  }
}

extern "C" void kernel_launch(void* const* d_in, const int* in_sizes, int n_in,
                              void* d_out, int out_size, void* d_ws, size_t ws_size,
                              hipStream_t stream) {
  const float* X = (const float*)d_in[0];   // inputs  [131072, 512] fp32
  const float* C = (const float*)d_in[1];   // clusters [512, 512] fp32
  float* out = (float*)d_out;               // [131072, 512] fp32

  short* Bp = (short*)d_ws;                                   // 512 KB packed bf16 clusters
  float* c2 = (float*)((char*)d_ws + (size_t)KC * DIM * 2);   // 2 KB cluster norms

  dec_pack<<<KC, 64, 0, stream>>>(C, Bp, c2);
  dec_main<<<NPTS / BM, 512, 0, stream>>>(X, Bp, c2, out);
}